// Round 1
// baseline (101.896 us; speedup 1.0000x reference)
//
#include <hip/hip_runtime.h>

typedef __attribute__((ext_vector_type(8))) short short8;
typedef __attribute__((ext_vector_type(4))) float f32x4;
typedef __attribute__((ext_vector_type(8))) unsigned short ushort8;

__device__ __forceinline__ unsigned short f2bf(float x) {
  union { float f; unsigned u; } v; v.f = x;
  unsigned r = v.u + 0x7fffu + ((v.u >> 16) & 1u);   // round-to-nearest-even
  return (unsigned short)(r >> 16);
}

// ---------------- fp32 -> bf16 bulk convert (8 elems/thread) ----------------
__global__ __launch_bounds__(256) void cvt_f32_bf16_kernel(
    const float* __restrict__ in, unsigned short* __restrict__ out, int n8) {
  int i = blockIdx.x * 256 + threadIdx.x;
  if (i >= n8) return;
  const float4* p = (const float4*)(in + (long)i * 8);
  float4 a = p[0], b = p[1];
  ushort8 o;
  o[0] = f2bf(a.x); o[1] = f2bf(a.y); o[2] = f2bf(a.z); o[3] = f2bf(a.w);
  o[4] = f2bf(b.x); o[5] = f2bf(b.y); o[6] = f2bf(b.z); o[7] = f2bf(b.w);
  *(ushort8*)(out + (long)i * 8) = o;
}

// ---------------- W[h][g] -> Wt[g][h] transpose + convert (512x512) ----------
__global__ __launch_bounds__(256) void wt_kernel(
    const float* __restrict__ W, unsigned short* __restrict__ Wt) {
  __shared__ float s[64][65];
  int g0 = blockIdx.x * 64, h0 = blockIdx.y * 64;
  int tx = threadIdx.x & 63, ty = threadIdx.x >> 6;  // ty in 0..3
#pragma unroll
  for (int rr = 0; rr < 16; ++rr) {
    int h = ty * 16 + rr;
    s[h][tx] = W[(long)(h0 + h) * 512 + g0 + tx];
  }
  __syncthreads();
#pragma unroll
  for (int rr = 0; rr < 16; ++rr) {
    int g = ty * 16 + rr;
    Wt[(long)(g0 + g) * 512 + h0 + tx] = f2bf(s[tx][g]);
  }
}

// ---------------- bf16 GEMM  C[M][N] = A[M][K] * Bt[N][K]^T (+bias) ----------
// m97-style: 128x128 tile, BK=32, 4 waves (2x2), 4x4 16x16x32 MFMA per wave,
// global_load_lds width=16 staging, single-buffered LDS, 2 barriers/K-step.
template <typename OutT, bool ADD_BIAS>
__global__ __launch_bounds__(256) void gemm_abt(
    const unsigned short* __restrict__ A, const unsigned short* __restrict__ Bt,
    OutT* __restrict__ C, int M, int N, int K,
    long sA, long sB, long sC, const float* __restrict__ bias) {
  constexpr int BM = 128, BN = 128, BK = 32;
  __shared__ __align__(16) short As[BM * BK];
  __shared__ __align__(16) short Bs[BN * BK];
  const int tid = threadIdx.x;
  const int wave = tid >> 6, lane = tid & 63;
  const int wm = wave >> 1, wn = wave & 1;
  const long z = blockIdx.z;
  const unsigned short* Ab = A + z * sA + (long)blockIdx.x * BM * K;
  const unsigned short* Bb = Bt + z * sB + (long)blockIdx.y * BN * K;
  const int r = lane & 15, q = lane >> 4;

  f32x4 acc[4][4] = {};

  for (int kt = 0; kt < K; kt += BK) {
    // stage A and B tiles: per wave, 2 issues each of 64 lanes x 16B = 1 KiB
#pragma unroll
    for (int j = 0; j < 2; ++j) {
      int c = (j * 4 + wave) * 64 + lane;      // 16B-chunk index in tile
      int row = c >> 2;                        // 4 chunks per 64B row (BK=32 bf16)
      int coff = (c & 3) * 8;                  // element offset within row
      __builtin_amdgcn_global_load_lds(
          (const __attribute__((address_space(1))) void*)(Ab + (long)row * K + kt + coff),
          (__attribute__((address_space(3))) void*)(As + (j * 4 + wave) * 512),
          16, 0, 0);
      __builtin_amdgcn_global_load_lds(
          (const __attribute__((address_space(1))) void*)(Bb + (long)row * K + kt + coff),
          (__attribute__((address_space(3))) void*)(Bs + (j * 4 + wave) * 512),
          16, 0, 0);
    }
    __syncthreads();  // drains vmcnt before barrier

    short8 af[4], bf[4];
#pragma unroll
    for (int m = 0; m < 4; ++m)
      af[m] = *(const short8*)&As[(wm * 64 + m * 16 + r) * BK + q * 8];
#pragma unroll
    for (int n = 0; n < 4; ++n)
      bf[n] = *(const short8*)&Bs[(wn * 64 + n * 16 + r) * BK + q * 8];

#pragma unroll
    for (int m = 0; m < 4; ++m)
#pragma unroll
      for (int n = 0; n < 4; ++n)
        acc[m][n] = __builtin_amdgcn_mfma_f32_16x16x32_bf16(af[m], bf[n], acc[m][n], 0, 0, 0);
    __syncthreads();
  }

  const float bv = ADD_BIAS ? bias[0] : 0.0f;
  OutT* Cb = C + z * sC;
  const long rowbase = (long)blockIdx.x * BM + wm * 64;
  const long colbase = (long)blockIdx.y * BN + wn * 64;
#pragma unroll
  for (int m = 0; m < 4; ++m) {
#pragma unroll
    for (int n = 0; n < 4; ++n) {
#pragma unroll
      for (int j = 0; j < 4; ++j) {
        long row = rowbase + m * 16 + q * 4 + j;   // C/D: row=(lane>>4)*4+reg
        long col = colbase + n * 16 + r;           // C/D: col=lane&15
        float v = acc[m][n][j] + bv;
        if constexpr (sizeof(OutT) == 2)
          Cb[row * (long)N + col] = (OutT)f2bf(v);
        else
          Cb[row * (long)N + col] = v;
      }
    }
  }
}

extern "C" void kernel_launch(void* const* d_in, const int* in_sizes, int n_in,
                              void* d_out, int out_size, void* d_ws, size_t ws_size,
                              hipStream_t stream) {
  const float* enc  = (const float*)d_in[0];  // [8,2048,512]
  const float* dec  = (const float*)d_in[1];  // [8,2048,512]
  const float* W    = (const float*)d_in[2];  // [1,512,512]
  const float* bias = (const float*)d_in[3];  // [1]
  float* out = (float*)d_out;                 // [8,2048,2048] fp32

  constexpr int Bn = 8, S = 2048, H = 512;
  constexpr long NE = (long)Bn * S * H;       // 8388608

  unsigned short* enc_bf = (unsigned short*)d_ws;        // 16.8 MB
  unsigned short* dec_bf = enc_bf + NE;                  // 16.8 MB
  unsigned short* Wt     = dec_bf + NE;                  // 0.5 MB
  unsigned short* encW   = Wt + (long)H * H;             // 16.8 MB

  cvt_f32_bf16_kernel<<<(int)(NE / 8 / 256), 256, 0, stream>>>(enc, enc_bf, (int)(NE / 8));
  cvt_f32_bf16_kernel<<<(int)(NE / 8 / 256), 256, 0, stream>>>(dec, dec_bf, (int)(NE / 8));
  wt_kernel<<<dim3(8, 8), 256, 0, stream>>>(W, Wt);

  // encW[b*S+e][g] = sum_h enc[b,e,h] * W[h,g]   (one big GEMM, W shared)
  gemm_abt<unsigned short, false><<<dim3((Bn * S) / 128, H / 128, 1), 256, 0, stream>>>(
      enc_bf, Wt, encW, Bn * S, H, H, 0, 0, 0, nullptr);

  // scores[b][d][e] = sum_g dec[b,d,g] * encW[b,e,g] + bias
  gemm_abt<float, true><<<dim3(S / 128, S / 128, Bn), 256, 0, stream>>>(
      dec_bf, encW, out, S, S, H, (long)S * H, (long)S * H, (long)S * S, bias);
}

// Round 2
// 91.531 us; speedup vs baseline: 1.1132x; 1.1132x over previous
//
#include <hip/hip_runtime.h>

typedef __attribute__((ext_vector_type(8))) short short8;
typedef __attribute__((ext_vector_type(4))) float f32x4;
typedef __attribute__((ext_vector_type(8))) unsigned short ushort8;

__device__ __forceinline__ unsigned short f2bf(float x) {
  union { float f; unsigned u; } v; v.f = x;
  unsigned r = v.u + 0x7fffu + ((v.u >> 16) & 1u);   // round-to-nearest-even
  return (unsigned short)(r >> 16);
}

// ---------------- fp32 -> bf16 bulk convert (8 elems/thread) ----------------
__global__ __launch_bounds__(256) void cvt_f32_bf16_kernel(
    const float* __restrict__ in, unsigned short* __restrict__ out, int n8) {
  int i = blockIdx.x * 256 + threadIdx.x;
  if (i >= n8) return;
  const float4* p = (const float4*)(in + (long)i * 8);
  float4 a = p[0], b = p[1];
  ushort8 o;
  o[0] = f2bf(a.x); o[1] = f2bf(a.y); o[2] = f2bf(a.z); o[3] = f2bf(a.w);
  o[4] = f2bf(b.x); o[5] = f2bf(b.y); o[6] = f2bf(b.z); o[7] = f2bf(b.w);
  *(ushort8*)(out + (long)i * 8) = o;
}

// ---------------- W[h][g] -> Wt[g][h] transpose + convert (512x512) ----------
__global__ __launch_bounds__(256) void wt_kernel(
    const float* __restrict__ W, unsigned short* __restrict__ Wt) {
  __shared__ float s[64][65];
  int g0 = blockIdx.x * 64, h0 = blockIdx.y * 64;
  int tx = threadIdx.x & 63, ty = threadIdx.x >> 6;
#pragma unroll
  for (int rr = 0; rr < 16; ++rr) {
    int h = ty * 16 + rr;
    s[h][tx] = W[(long)(h0 + h) * 512 + g0 + tx];
  }
  __syncthreads();
#pragma unroll
  for (int rr = 0; rr < 16; ++rr) {
    int g = ty * 16 + rr;
    Wt[(long)(g0 + g) * 512 + h0 + tx] = f2bf(s[tx][g]);
  }
}

// ---------------- GEMM1 (m97-style 128x128): encW = enc_bf @ Wt^T -----------
__global__ __launch_bounds__(256) void gemm1_abt(
    const unsigned short* __restrict__ A, const unsigned short* __restrict__ Bt,
    unsigned short* __restrict__ C, int M, int N, int K) {
  constexpr int BK = 32;
  __shared__ __align__(16) short As[128 * BK];
  __shared__ __align__(16) short Bs[128 * BK];
  const int tid = threadIdx.x;
  const int wave = tid >> 6, lane = tid & 63;
  const int wm = wave >> 1, wn = wave & 1;
  const unsigned short* Ab = A + (long)blockIdx.x * 128 * K;
  const unsigned short* Bb = Bt + (long)blockIdx.y * 128 * K;
  const int r = lane & 15, q = lane >> 4;

  f32x4 acc[4][4] = {};

  for (int kt = 0; kt < K; kt += BK) {
#pragma unroll
    for (int j = 0; j < 2; ++j) {
      int c = (j * 4 + wave) * 64 + lane;
      int row = c >> 2;
      int coff = (c & 3) * 8;
      __builtin_amdgcn_global_load_lds(
          (const __attribute__((address_space(1))) void*)(Ab + (long)row * K + kt + coff),
          (__attribute__((address_space(3))) void*)(As + (j * 4 + wave) * 512),
          16, 0, 0);
      __builtin_amdgcn_global_load_lds(
          (const __attribute__((address_space(1))) void*)(Bb + (long)row * K + kt + coff),
          (__attribute__((address_space(3))) void*)(Bs + (j * 4 + wave) * 512),
          16, 0, 0);
    }
    __syncthreads();

    short8 af[4], bfr[4];
#pragma unroll
    for (int m = 0; m < 4; ++m)
      af[m] = *(const short8*)&As[(wm * 64 + m * 16 + r) * BK + q * 8];
#pragma unroll
    for (int n = 0; n < 4; ++n)
      bfr[n] = *(const short8*)&Bs[(wn * 64 + n * 16 + r) * BK + q * 8];

#pragma unroll
    for (int m = 0; m < 4; ++m)
#pragma unroll
      for (int n = 0; n < 4; ++n)
        acc[m][n] = __builtin_amdgcn_mfma_f32_16x16x32_bf16(af[m], bfr[n], acc[m][n], 0, 0, 0);
    __syncthreads();
  }

  const long rowbase = (long)blockIdx.x * 128 + wm * 64;
  const long colbase = (long)blockIdx.y * 128 + wn * 64;
#pragma unroll
  for (int m = 0; m < 4; ++m)
#pragma unroll
    for (int n = 0; n < 4; ++n)
#pragma unroll
      for (int j = 0; j < 4; ++j) {
        long row = rowbase + m * 16 + q * 4 + j;
        long col = colbase + n * 16 + r;
        C[row * (long)N + col] = f2bf(acc[m][n][j]);
      }
}

// ---------------- GEMM2: 256x256 8-phase (T1+T2+T3+T4+T5) --------------------
// scores[b][d][e] = sum_g dec_bf[b,d,g] * encW[b,e,g] + bias
// BM=BN=256, BK=64, 512 thr (2Mx4N waves). LDS 128KB: A dbuf 2x32KB, B dbuf 2x32KB.
// Each 32KB tile = 2 k-halves (kk in {0,1}) of 16KB = 16 subtiles (16 rows x 32 k-cols,
// 1024B) with st_16x32 swizzle: byte ^= ((byte>>9)&1)<<5 within each subtile.
// global_load_lds writes linearly; the global SOURCE is pre-swizzled to match (rule 21).

#define VMCNT(n) asm volatile("s_waitcnt vmcnt(" #n ")" ::: "memory")

#define STAGE(GP, LBASE, tt, kkv)                                             \
  do {                                                                        \
    _Pragma("unroll") for (int j_ = 0; j_ < 2; ++j_) {                        \
      int c_ = w * 2 + j_;                                                    \
      __builtin_amdgcn_global_load_lds(                                       \
          (const __attribute__((address_space(1))) void*)(                    \
              (GP) + ((long)(c_ * 16 + srow)) * 512 + (tt) * 64 + (kkv) * 32 + scol), \
          (__attribute__((address_space(3))) void*)((LBASE) + (c_ << 10)),    \
          16, 0, 0);                                                          \
    }                                                                         \
  } while (0)

#define PHASE(Ac, Bc, kkv, mb, LOADB, STAGE_STMT, ENDWAIT_STMT)               \
  do {                                                                        \
    if (LOADB) {                                                              \
      _Pragma("unroll") for (int n_ = 0; n_ < 4; ++n_)                        \
        bf[kkv][n_] = *(const short8*)((Bc) + (kkv) * 16384 +                 \
                                       ((wn * 4 + n_) << 10) + lconst);       \
    }                                                                         \
    _Pragma("unroll") for (int i_ = 0; i_ < 4; ++i_)                          \
      af[i_] = *(const short8*)((Ac) + (kkv) * 16384 +                        \
                                ((wm * 8 + (mb) + i_) << 10) + lconst);       \
    STAGE_STMT;                                                               \
    __builtin_amdgcn_s_barrier();                                             \
    asm volatile("s_waitcnt lgkmcnt(0)" ::: "memory");                        \
    __builtin_amdgcn_sched_barrier(0);                                        \
    __builtin_amdgcn_s_setprio(1);                                            \
    _Pragma("unroll") for (int i_ = 0; i_ < 4; ++i_)                          \
      _Pragma("unroll") for (int n_ = 0; n_ < 4; ++n_)                        \
        acc[(mb) + i_][n_] = __builtin_amdgcn_mfma_f32_16x16x32_bf16(         \
            af[i_], bf[kkv][n_], acc[(mb) + i_][n_], 0, 0, 0);                \
    __builtin_amdgcn_s_setprio(0);                                            \
    ENDWAIT_STMT;                                                             \
    __builtin_amdgcn_s_barrier();                                             \
  } while (0)

__global__ __launch_bounds__(512, 2) void gemm2_8ph(
    const unsigned short* __restrict__ A,   // dec_bf  [8*2048][512]
    const unsigned short* __restrict__ Bt,  // encW    [8*2048][512]
    float* __restrict__ C, const float* __restrict__ bias) {
  __shared__ __align__(16) char Lds[131072];
#define LDS_A(d) (Lds + (d) * 32768)
#define LDS_B(d) (Lds + 65536 + (d) * 32768)

  // bijective XCD swizzle: 512 blocks, 64/XCD -> one batch per XCD (4MB L2 fit)
  int flat = blockIdx.x;
  int sw = (flat & 7) * 64 + (flat >> 3);
  int z = sw >> 6, xy = sw & 63, bx = xy & 7, by = xy >> 3;

  const int tid = threadIdx.x;
  const int w = tid >> 6, lane = tid & 63;
  const int wm = w >> 2, wn = w & 3;            // 2 x 4 waves, per-wave 128x64 out
  const int base_r = lane & 15, q = lane >> 4;
  // swizzled ds_read offset within a 1024B subtile (r&8 flips byte-bit-5)
  const int lconst = base_r * 64 + ((q * 16) ^ ((base_r & 8) << 2));
  // staging source pre-swizzle: lane -> (row, col) of linear LDS chunk content
  const int srow = lane >> 2;                               // + chunk*16
  const int scol = ((lane & 3) * 8) ^ (((lane >> 5) & 1) << 4);

  const unsigned short* Ab = A + ((long)z * 2048 + bx * 256) * 512;
  const unsigned short* Bb = Bt + ((long)z * 2048 + by * 256) * 512;

  f32x4 acc[8][4] = {};
  short8 af[4];
  short8 bf[2][4];

  // prologue: stage tile 0 (Ak0,Bk0,Ak1,Bk1), wait for the first two halves
  STAGE(Ab, LDS_A(0), 0, 0);
  STAGE(Bb, LDS_B(0), 0, 0);
  STAGE(Ab, LDS_A(0) + 16384, 0, 1);
  STAGE(Bb, LDS_B(0) + 16384, 0, 1);
  VMCNT(4);
  __builtin_amdgcn_s_barrier();

  // main: tiles 0..6 compute, staging tile t+1 (counted vmcnt(4), never 0)
  for (int t = 0; t < 7; ++t) {
    const char* Ac = LDS_A(t & 1);
    const char* Bc = LDS_B(t & 1);
    char* An = LDS_A((t + 1) & 1);
    char* Bn = LDS_B((t + 1) & 1);
    PHASE(Ac, Bc, 0, 0, true,  STAGE(Ab, An, t + 1, 0),         (void)0);
    PHASE(Ac, Bc, 0, 4, false, STAGE(Bb, Bn, t + 1, 0),         VMCNT(4));
    PHASE(Ac, Bc, 1, 0, true,  STAGE(Ab, An + 16384, t + 1, 1), (void)0);
    PHASE(Ac, Bc, 1, 4, false, STAGE(Bb, Bn + 16384, t + 1, 1), VMCNT(4));
  }
  // tail: tile 7, no staging; drain remaining k1 loads before phase 2
  {
    const char* Ac = LDS_A(1);
    const char* Bc = LDS_B(1);
    PHASE(Ac, Bc, 0, 0, true,  (void)0, (void)0);
    PHASE(Ac, Bc, 0, 4, false, (void)0, VMCNT(0));
    PHASE(Ac, Bc, 1, 0, true,  (void)0, (void)0);
    PHASE(Ac, Bc, 1, 4, false, (void)0, (void)0);
  }

  const float bv = bias[0];
  float* Cb = C + ((long)z * 2048 + bx * 256 + wm * 128) * 2048 + by * 256 + wn * 64;
#pragma unroll
  for (int m = 0; m < 8; ++m)
#pragma unroll
    for (int n = 0; n < 4; ++n)
#pragma unroll
      for (int j = 0; j < 4; ++j)
        Cb[(long)(m * 16 + q * 4 + j) * 2048 + n * 16 + base_r] = acc[m][n][j] + bv;
#undef LDS_A
#undef LDS_B
}

extern "C" void kernel_launch(void* const* d_in, const int* in_sizes, int n_in,
                              void* d_out, int out_size, void* d_ws, size_t ws_size,
                              hipStream_t stream) {
  const float* enc  = (const float*)d_in[0];  // [8,2048,512]
  const float* dec  = (const float*)d_in[1];  // [8,2048,512]
  const float* W    = (const float*)d_in[2];  // [1,512,512]
  const float* bias = (const float*)d_in[3];  // [1]
  float* out = (float*)d_out;                 // [8,2048,2048] fp32

  constexpr int Bn = 8, S = 2048, H = 512;
  constexpr long NE = (long)Bn * S * H;       // 8388608

  unsigned short* enc_bf = (unsigned short*)d_ws;        // 16.8 MB
  unsigned short* dec_bf = enc_bf + NE;                  // 16.8 MB
  unsigned short* Wt     = dec_bf + NE;                  // 0.5 MB
  unsigned short* encW   = Wt + (long)H * H;             // 16.8 MB

  cvt_f32_bf16_kernel<<<(int)(NE / 8 / 256), 256, 0, stream>>>(enc, enc_bf, (int)(NE / 8));
  cvt_f32_bf16_kernel<<<(int)(NE / 8 / 256), 256, 0, stream>>>(dec, dec_bf, (int)(NE / 8));
  wt_kernel<<<dim3(8, 8), 256, 0, stream>>>(W, Wt);

  // encW[b*S+e][g] = sum_h enc[b,e,h] * W[h,g]
  gemm1_abt<<<dim3((Bn * S) / 128, H / 128, 1), 256, 0, stream>>>(
      enc_bf, Wt, encW, Bn * S, H, H);

  // scores[b][d][e] = dec[b,d,:] . encW[b,e,:] + bias
  gemm2_8ph<<<dim3(512, 1, 1), 512, 0, stream>>>(dec_bf, encW, out, bias);
}

// Round 3
// 83.472 us; speedup vs baseline: 1.2207x; 1.0965x over previous
//
#include <hip/hip_runtime.h>

typedef __attribute__((ext_vector_type(8))) short short8;
typedef __attribute__((ext_vector_type(4))) float f32x4;
typedef __attribute__((ext_vector_type(8))) unsigned short ushort8;

__device__ __forceinline__ unsigned short f2bf(float x) {
  union { float f; unsigned u; } v; v.f = x;
  unsigned r = v.u + 0x7fffu + ((v.u >> 16) & 1u);   // round-to-nearest-even
  return (unsigned short)(r >> 16);
}

// ---------------- W[h][g] -> Wt[g][h] transpose + convert (512x512) ----------
__global__ __launch_bounds__(256) void wt_kernel(
    const float* __restrict__ W, unsigned short* __restrict__ Wt) {
  __shared__ float s[64][65];
  int g0 = blockIdx.x * 64, h0 = blockIdx.y * 64;
  int tx = threadIdx.x & 63, ty = threadIdx.x >> 6;
#pragma unroll
  for (int rr = 0; rr < 16; ++rr) {
    int h = ty * 16 + rr;
    s[h][tx] = W[(long)(h0 + h) * 512 + g0 + tx];
  }
  __syncthreads();
#pragma unroll
  for (int rr = 0; rr < 16; ++rr) {
    int g = ty * 16 + rr;
    Wt[(long)(g0 + g) * 512 + h0 + tx] = f2bf(s[tx][g]);
  }
}

// ---- Fused: gemm1 (blocks 0..511) + dec fp32->bf16 convert (blocks 512..4607)
// gemm1: encW[m][g] = sum_h enc[m][h] * Wt[g][h], m in [0,16384), g in [0,512)
//   A (enc) is fp32: reg-staged with on-the-fly cvt (global->reg->cvt->ds_write).
//   B (Wt) is bf16: global_load_lds width-16 as in m97.
__global__ __launch_bounds__(256) void gemm1_plus_cvtdec(
    const float* __restrict__ enc, const unsigned short* __restrict__ Wt,
    unsigned short* __restrict__ encW,
    const float* __restrict__ dec, unsigned short* __restrict__ dec_bf) {
  if (blockIdx.x >= 512) {
    // ---- dec conversion path: 4096 blocks x 256 thr x 8 elems = 8388608
    int i = (blockIdx.x - 512) * 256 + threadIdx.x;
    const float4* p = (const float4*)(dec + (long)i * 8);
    float4 a = p[0], b = p[1];
    ushort8 o;
    o[0] = f2bf(a.x); o[1] = f2bf(a.y); o[2] = f2bf(a.z); o[3] = f2bf(a.w);
    o[4] = f2bf(b.x); o[5] = f2bf(b.y); o[6] = f2bf(b.z); o[7] = f2bf(b.w);
    *(ushort8*)(dec_bf + (long)i * 8) = o;
    return;
  }

  // ---- gemm1 path
  constexpr int K = 512, N = 512, BK = 32;
  __shared__ __align__(16) short As[128 * BK];   // 8KB
  __shared__ __align__(16) short Bs[128 * BK];   // 8KB

  // XCD grouping: the 4 N-tiles sharing an A-panel stay on one XCD
  const int g = blockIdx.x;
  const int work = (g & 7) * 64 + (g >> 3);      // bijective on [0,512)
  const int bxm = work >> 2, byn = work & 3;

  const int tid = threadIdx.x;
  const int wave = tid >> 6, lane = tid & 63;
  const int wm = wave >> 1, wn = wave & 1;
  const int r = lane & 15, q = lane >> 4;

  const float* Ab = enc + (long)bxm * 128 * K;
  const unsigned short* Bb = Wt + (long)byn * 128 * K;

  // A staging geometry: 2 threads per row, 16 fp32 (64B) each
  const int srow = tid >> 1, shalf = tid & 1;
  const float* arow = Ab + (long)srow * K + shalf * 16;

  f32x4 acc[4][4] = {};
  float4 av[4];
#pragma unroll
  for (int j = 0; j < 4; ++j) av[j] = ((const float4*)arow)[j];

  for (int kt = 0; kt < K; kt += BK) {
    // convert the prefetched A regs -> LDS (As[row][k], 128x32 bf16 linear)
    ushort8 o0, o1;
    o0[0] = f2bf(av[0].x); o0[1] = f2bf(av[0].y); o0[2] = f2bf(av[0].z); o0[3] = f2bf(av[0].w);
    o0[4] = f2bf(av[1].x); o0[5] = f2bf(av[1].y); o0[6] = f2bf(av[1].z); o0[7] = f2bf(av[1].w);
    o1[0] = f2bf(av[2].x); o1[1] = f2bf(av[2].y); o1[2] = f2bf(av[2].z); o1[3] = f2bf(av[2].w);
    o1[4] = f2bf(av[3].x); o1[5] = f2bf(av[3].y); o1[6] = f2bf(av[3].z); o1[7] = f2bf(av[3].w);
    *(ushort8*)&As[srow * BK + shalf * 16 + 0] = o0;
    *(ushort8*)&As[srow * BK + shalf * 16 + 8] = o1;

    // B tile via global_load_lds (2 issues/wave, 16B/lane)
#pragma unroll
    for (int j = 0; j < 2; ++j) {
      int c = (j * 4 + wave) * 64 + lane;
      int row = c >> 2;
      int coff = (c & 3) * 8;
      __builtin_amdgcn_global_load_lds(
          (const __attribute__((address_space(1))) void*)(Bb + (long)row * K + kt + coff),
          (__attribute__((address_space(3))) void*)(Bs + (j * 4 + wave) * 512),
          16, 0, 0);
    }
    __syncthreads();

    short8 af[4], bfr[4];
#pragma unroll
    for (int m = 0; m < 4; ++m)
      af[m] = *(const short8*)&As[(wm * 64 + m * 16 + r) * BK + q * 8];
#pragma unroll
    for (int n = 0; n < 4; ++n)
      bfr[n] = *(const short8*)&Bs[(wn * 64 + n * 16 + r) * BK + q * 8];

    // prefetch next A k-slice into regs during compute (latency hides under MFMA)
    if (kt + BK < K) {
      const float* ap = arow + kt + BK;
#pragma unroll
      for (int j = 0; j < 4; ++j) av[j] = ((const float4*)ap)[j];
    }

#pragma unroll
    for (int m = 0; m < 4; ++m)
#pragma unroll
      for (int n = 0; n < 4; ++n)
        acc[m][n] = __builtin_amdgcn_mfma_f32_16x16x32_bf16(af[m], bfr[n], acc[m][n], 0, 0, 0);
    __syncthreads();
  }

  const long rowbase = (long)bxm * 128 + wm * 64;
  const long colbase = (long)byn * 128 + wn * 64;
#pragma unroll
  for (int m = 0; m < 4; ++m)
#pragma unroll
    for (int n = 0; n < 4; ++n)
#pragma unroll
      for (int j = 0; j < 4; ++j) {
        long row = rowbase + m * 16 + q * 4 + j;
        long col = colbase + n * 16 + r;
        encW[row * (long)N + col] = f2bf(acc[m][n][j]);
      }
}

// ---------------- GEMM2: 256x256 8-phase (T1+T2+T3+T4+T5) --------------------
// scores[b][d][e] = sum_g dec_bf[b,d,g] * encW[b,e,g] + bias

#define VMCNT(n) asm volatile("s_waitcnt vmcnt(" #n ")" ::: "memory")

#define STAGE(GP, LBASE, tt, kkv)                                             \
  do {                                                                        \
    _Pragma("unroll") for (int j_ = 0; j_ < 2; ++j_) {                        \
      int c_ = w * 2 + j_;                                                    \
      __builtin_amdgcn_global_load_lds(                                       \
          (const __attribute__((address_space(1))) void*)(                    \
              (GP) + ((long)(c_ * 16 + srow)) * 512 + (tt) * 64 + (kkv) * 32 + scol), \
          (__attribute__((address_space(3))) void*)((LBASE) + (c_ << 10)),    \
          16, 0, 0);                                                          \
    }                                                                         \
  } while (0)

#define PHASE(Ac, Bc, kkv, mb, LOADB, STAGE_STMT, ENDWAIT_STMT)               \
  do {                                                                        \
    if (LOADB) {                                                              \
      _Pragma("unroll") for (int n_ = 0; n_ < 4; ++n_)                        \
        bf[kkv][n_] = *(const short8*)((Bc) + (kkv) * 16384 +                 \
                                       ((wn * 4 + n_) << 10) + lconst);       \
    }                                                                         \
    _Pragma("unroll") for (int i_ = 0; i_ < 4; ++i_)                          \
      af[i_] = *(const short8*)((Ac) + (kkv) * 16384 +                        \
                                ((wm * 8 + (mb) + i_) << 10) + lconst);       \
    STAGE_STMT;                                                               \
    __builtin_amdgcn_s_barrier();                                             \
    asm volatile("s_waitcnt lgkmcnt(0)" ::: "memory");                        \
    __builtin_amdgcn_sched_barrier(0);                                        \
    __builtin_amdgcn_s_setprio(1);                                            \
    _Pragma("unroll") for (int i_ = 0; i_ < 4; ++i_)                          \
      _Pragma("unroll") for (int n_ = 0; n_ < 4; ++n_)                        \
        acc[(mb) + i_][n_] = __builtin_amdgcn_mfma_f32_16x16x32_bf16(         \
            af[i_], bf[kkv][n_], acc[(mb) + i_][n_], 0, 0, 0);                \
    __builtin_amdgcn_s_setprio(0);                                            \
    ENDWAIT_STMT;                                                             \
    __builtin_amdgcn_s_barrier();                                             \
  } while (0)

__global__ __launch_bounds__(512, 2) void gemm2_8ph(
    const unsigned short* __restrict__ A,   // dec_bf  [8*2048][512]
    const unsigned short* __restrict__ Bt,  // encW    [8*2048][512]
    float* __restrict__ C, const float* __restrict__ bias) {
  __shared__ __align__(16) char Lds[131072];
#define LDS_A(d) (Lds + (d) * 32768)
#define LDS_B(d) (Lds + 65536 + (d) * 32768)

  // bijective XCD swizzle: 512 blocks, 64/XCD -> one batch per XCD (4MB L2 fit)
  int flat = blockIdx.x;
  int sw = (flat & 7) * 64 + (flat >> 3);
  int z = sw >> 6, xy = sw & 63, bx = xy & 7, by = xy >> 3;

  const int tid = threadIdx.x;
  const int w = tid >> 6, lane = tid & 63;
  const int wm = w >> 2, wn = w & 3;            // 2 x 4 waves, per-wave 128x64 out
  const int base_r = lane & 15, q = lane >> 4;
  const int lconst = base_r * 64 + ((q * 16) ^ ((base_r & 8) << 2));
  const int srow = lane >> 2;
  const int scol = ((lane & 3) * 8) ^ (((lane >> 5) & 1) << 4);

  const unsigned short* Ab = A + ((long)z * 2048 + bx * 256) * 512;
  const unsigned short* Bb = Bt + ((long)z * 2048 + by * 256) * 512;

  f32x4 acc[8][4] = {};
  short8 af[4];
  short8 bf[2][4];

  STAGE(Ab, LDS_A(0), 0, 0);
  STAGE(Bb, LDS_B(0), 0, 0);
  STAGE(Ab, LDS_A(0) + 16384, 0, 1);
  STAGE(Bb, LDS_B(0) + 16384, 0, 1);
  VMCNT(4);
  __builtin_amdgcn_s_barrier();

  for (int t = 0; t < 7; ++t) {
    const char* Ac = LDS_A(t & 1);
    const char* Bc = LDS_B(t & 1);
    char* An = LDS_A((t + 1) & 1);
    char* Bn = LDS_B((t + 1) & 1);
    PHASE(Ac, Bc, 0, 0, true,  STAGE(Ab, An, t + 1, 0),         (void)0);
    PHASE(Ac, Bc, 0, 4, false, STAGE(Bb, Bn, t + 1, 0),         VMCNT(4));
    PHASE(Ac, Bc, 1, 0, true,  STAGE(Ab, An + 16384, t + 1, 1), (void)0);
    PHASE(Ac, Bc, 1, 4, false, STAGE(Bb, Bn + 16384, t + 1, 1), VMCNT(4));
  }
  {
    const char* Ac = LDS_A(1);
    const char* Bc = LDS_B(1);
    PHASE(Ac, Bc, 0, 0, true,  (void)0, (void)0);
    PHASE(Ac, Bc, 0, 4, false, (void)0, VMCNT(0));
    PHASE(Ac, Bc, 1, 0, true,  (void)0, (void)0);
    PHASE(Ac, Bc, 1, 4, false, (void)0, (void)0);
  }

  const float bv = bias[0];
  float* Cb = C + ((long)z * 2048 + bx * 256 + wm * 128) * 2048 + by * 256 + wn * 64;
#pragma unroll
  for (int m = 0; m < 8; ++m)
#pragma unroll
    for (int n = 0; n < 4; ++n)
#pragma unroll
      for (int j = 0; j < 4; ++j)
        Cb[(long)(m * 16 + q * 4 + j) * 2048 + n * 16 + base_r] = acc[m][n][j] + bv;
#undef LDS_A
#undef LDS_B
}

extern "C" void kernel_launch(void* const* d_in, const int* in_sizes, int n_in,
                              void* d_out, int out_size, void* d_ws, size_t ws_size,
                              hipStream_t stream) {
  const float* enc  = (const float*)d_in[0];  // [8,2048,512]
  const float* dec  = (const float*)d_in[1];  // [8,2048,512]
  const float* W    = (const float*)d_in[2];  // [1,512,512]
  const float* bias = (const float*)d_in[3];  // [1]
  float* out = (float*)d_out;                 // [8,2048,2048] fp32

  constexpr int Bn = 8, S = 2048, H = 512;
  constexpr long NE = (long)Bn * S * H;       // 8388608

  unsigned short* dec_bf = (unsigned short*)d_ws;        // 16.8 MB
  unsigned short* Wt     = dec_bf + NE;                  // 0.5 MB
  unsigned short* encW   = Wt + (long)H * H;             // 16.8 MB

  wt_kernel<<<dim3(8, 8), 256, 0, stream>>>(W, Wt);

  // gemm1 (512 blocks) + dec conversion (4096 blocks) in one launch
  gemm1_plus_cvtdec<<<dim3(512 + 4096, 1, 1), 256, 0, stream>>>(
      enc, Wt, encW, dec, dec_bf);

  // scores[b][d][e] = dec[b,d,:] . encW[b,e,:] + bias
  gemm2_8ph<<<dim3(512, 1, 1), 512, 0, stream>>>(dec_bf, encW, out, bias);
}